// Round 1
// baseline (385.423 us; speedup 1.0000x reference)
//
#include <hip/hip_runtime.h>

#define EPS_F 1e-5f

constexpr int TQ = 64;      // queries per block
constexpr int TK = 64;      // keys per tile
constexpr int DH = 64;      // head dim (= dv)
constexpr int NT = 256;     // threads per block

// Swizzled float4 index within a [64][16] float4 tile.
// Physical column = (c4 + (row>>2)) & 15 -> score-phase reads (16 rows, fixed c4)
// spread over all 8 16B-bank-groups with only 2-way aliasing (free per m136).
__device__ __forceinline__ int swz(int row, int c4) {
    return (row << 4) | ((c4 + (row >> 2)) & 15);
}

__global__ __launch_bounds__(NT, 2) void attn_pow2_f32(
    const float* __restrict__ Qg, const float* __restrict__ Kg,
    const float* __restrict__ Vg, float* __restrict__ Og,
    int B, int T, int H)
{
    __shared__ float4 smem4[4096];            // 64 KiB exactly
    float4* const Qs = smem4;                 // [64][16] f4
    float4* const Ks = smem4 + 1024;
    float4* const Vs = smem4 + 2048;
    float4* const Ss = smem4 + 3072;          // score tile
    float*  const DenP = (float*)(smem4 + 3072); // alias Ss (used after last PV)
    float*  const Zs   = (float*)smem4;          // alias Qs (used after last score)

    const int tid = threadIdx.x;
    const int qt  = (int)(gridDim.x - 1 - blockIdx.x);   // heavy blocks first
    const int bh  = (int)blockIdx.y;
    const int b = bh / H, h = bh % H;
    const int q0 = qt * TQ;

    const int rs4 = H * DH / 4;               // time-row stride in float4 (=128)
    const size_t base4 = (size_t)b * T * rs4 + (size_t)h * (DH / 4);

    const float4* Qg4 = (const float4*)Qg;
    const float4* Kg4 = (const float4*)Kg;
    const float4* Vg4 = (const float4*)Vg;
    float4* Og4 = (float4*)Og;

    // ---- stage Q tile (64 rows x 64 f32) ----
    #pragma unroll
    for (int j = 0; j < 4; ++j) {
        int f4 = (j << 8) + tid;
        int row = f4 >> 4, c4 = f4 & 15;
        Qs[swz(row, c4)] = Qg4[base4 + (size_t)(q0 + row) * rs4 + c4];
    }

    const int tq = tid & 15;     // q-group of 4 rows (score, PV, epilogue)
    const int tk = tid >> 4;     // k-group of 4 (score) / v-group of 4 (PV)

    float4 acc[4];
    #pragma unroll
    for (int r = 0; r < 4; ++r) acc[r] = make_float4(0.f, 0.f, 0.f, 0.f);
    float den[4] = {0.f, 0.f, 0.f, 0.f};

    for (int kt = 0; kt <= qt; ++kt) {
        __syncthreads();                      // prev PV done with Ks/Vs/Ss
        // ---- stage K/V tiles ----
        #pragma unroll
        for (int j = 0; j < 4; ++j) {
            int f4 = (j << 8) + tid;
            int row = f4 >> 4, c4 = f4 & 15;
            size_t g = base4 + (size_t)(kt * TK + row) * rs4 + c4;
            Ks[swz(row, c4)] = Kg4[g];
            Vs[swz(row, c4)] = Vg4[g];
        }
        __syncthreads();

        // ---- scores: c[r][s] = q_{4tq+r} . k_{4tk+s} (4x4 per thread) ----
        float c[4][4];
        #pragma unroll
        for (int r = 0; r < 4; ++r)
            #pragma unroll
            for (int s = 0; s < 4; ++s) c[r][s] = 0.f;

        for (int i4 = 0; i4 < 16; ++i4) {
            float4 qv[4], kv[4];
            #pragma unroll
            for (int r = 0; r < 4; ++r) qv[r] = Qs[swz(4 * tq + r, i4)];
            #pragma unroll
            for (int s = 0; s < 4; ++s) kv[s] = Ks[swz(4 * tk + s, i4)];
            #pragma unroll
            for (int r = 0; r < 4; ++r)
                #pragma unroll
                for (int s = 0; s < 4; ++s)
                    c[r][s] += qv[r].x * kv[s].x + qv[r].y * kv[s].y
                             + qv[r].z * kv[s].z + qv[r].w * kv[s].w;
        }

        // square, causal-mask (diagonal tile only), accumulate denominator
        const bool diag = (kt == qt);
        #pragma unroll
        for (int r = 0; r < 4; ++r) {
            float sc[4];
            #pragma unroll
            for (int s = 0; s < 4; ++s) {
                float dot = c[r][s];
                float v = dot * dot;
                if (diag && (4 * tk + s) > (4 * tq + r)) v = 0.f;
                sc[s] = v;
                den[r] += v;
            }
            Ss[swz(4 * tq + r, tk)] = make_float4(sc[0], sc[1], sc[2], sc[3]);
        }
        __syncthreads();

        // ---- PV: acc[q][v] += sum_k S[q][k] * V[k][v] ----
        for (int k4 = 0; k4 < 16; ++k4) {
            float4 sv[4], vv[4];
            #pragma unroll
            for (int r = 0; r < 4; ++r) sv[r] = Ss[swz(4 * tq + r, k4)];
            #pragma unroll
            for (int m = 0; m < 4; ++m) vv[m] = Vs[swz(4 * k4 + m, tk)];
            #pragma unroll
            for (int r = 0; r < 4; ++r) {
                acc[r].x += sv[r].x * vv[0].x + sv[r].y * vv[1].x + sv[r].z * vv[2].x + sv[r].w * vv[3].x;
                acc[r].y += sv[r].x * vv[0].y + sv[r].y * vv[1].y + sv[r].z * vv[2].y + sv[r].w * vv[3].y;
                acc[r].z += sv[r].x * vv[0].z + sv[r].y * vv[1].z + sv[r].z * vv[2].z + sv[r].w * vv[3].z;
                acc[r].w += sv[r].x * vv[0].w + sv[r].y * vv[1].w + sv[r].z * vv[2].w + sv[r].w * vv[3].w;
            }
        }
    }

    // ---- reduce denominator across the 16 k-groups, then divide + store ----
    __syncthreads();
    #pragma unroll
    for (int r = 0; r < 4; ++r) DenP[(4 * tq + r) * 17 + tk] = den[r];
    __syncthreads();
    if (tid < TQ) {
        float z = EPS_F;
        #pragma unroll
        for (int g = 0; g < 16; ++g) z += DenP[tid * 17 + g];
        Zs[tid] = z;
    }
    __syncthreads();
    #pragma unroll
    for (int r = 0; r < 4; ++r) {
        float invz = 1.0f / Zs[4 * tq + r];
        float4 o = make_float4(acc[r].x * invz, acc[r].y * invz,
                               acc[r].z * invz, acc[r].w * invz);
        Og4[base4 + (size_t)(q0 + 4 * tq + r) * rs4 + tk] = o;
    }
}

extern "C" void kernel_launch(void* const* d_in, const int* in_sizes, int n_in,
                              void* d_out, int out_size, void* d_ws, size_t ws_size,
                              hipStream_t stream) {
    const float* Q = (const float*)d_in[0];
    const float* K = (const float*)d_in[1];
    const float* V = (const float*)d_in[2];
    float* O = (float*)d_out;
    const int B = 2, T = 2048, H = 8;
    dim3 grid(T / TQ, B * H);   // 32 x 16 = 512 blocks
    attn_pow2_f32<<<grid, NT, 0, stream>>>(Q, K, V, O, B, T, H);
}

// Round 2
// 144.569 us; speedup vs baseline: 2.6660x; 2.6660x over previous
//
#include <hip/hip_runtime.h>

typedef __attribute__((ext_vector_type(8))) short bf16x8;   // 8 bf16 = 4 VGPRs
typedef __attribute__((ext_vector_type(4))) float f32x4;

constexpr int NT   = 256;
constexpr int DH   = 64;
constexpr int LSTR = 72;            // shorts per LDS row (64 data + 8 pad = 144 B)
constexpr int TILE = 64 * LSTR;     // 4608 shorts per 64-row tile

__device__ __forceinline__ unsigned short f2bf(float x) {   // round-to-nearest-even
    unsigned u = __builtin_bit_cast(unsigned, x);
    unsigned r = u + 0x7FFFu + ((u >> 16) & 1u);
    return (unsigned short)(r >> 16);
}
__device__ __forceinline__ float bf2f(unsigned short h) {
    unsigned u = ((unsigned)h) << 16;
    return __builtin_bit_cast(float, u);
}

__global__ __launch_bounds__(NT, 2) void attn_pow2_mfma(
    const float* __restrict__ Qg, const float* __restrict__ Kg,
    const float* __restrict__ Vg, float* __restrict__ Og,
    int B, int T, int H)
{
    __shared__ short lds[7 * TILE];          // 64512 B
    short* const Qh = lds;
    short* const Ql = lds + 1 * TILE;
    short* const Kh = lds + 2 * TILE;
    short* const Kl = lds + 3 * TILE;
    short* const Vt = lds + 4 * TILE;        // V^T: [v][k]
    short* const Sh = lds + 5 * TILE;
    short* const Sl = lds + 6 * TILE;
    float* const Vf = (float*)(lds + 5 * TILE);  // f32 V staging, aliases Sh/Sl (64x68 f32)

    const int tid  = threadIdx.x;
    const int lane = tid & 63;
    const int wave = tid >> 6;               // 4 waves; m-strip = wave*16
    const int a    = lane & 15;
    const int quad = lane >> 4;
    const int m0   = wave * 16;

    // load-balance swizzle: ranks r and 511-r (heavy+light) land on the same CU
    int r0 = (int)blockIdx.x;
    int wr = (r0 < 256) ? r0 : (767 - r0);
    const int qt = 31 - (wr >> 4);           // query-tile index, heavy-first
    const int bh = wr & 15;
    const int b = bh >> 3, h = bh & 7;
    const int q0 = qt * 64;

    const int rs4 = H * DH / 4;              // 128 float4 per time row
    const size_t base4 = (size_t)b * T * rs4 + (size_t)h * (DH / 4);
    const float4* Qg4 = (const float4*)Qg;
    const float4* Kg4 = (const float4*)Kg;
    const float4* Vg4 = (const float4*)Vg;

    // ---- stage Q tile as bf16 hi/lo ----
    #pragma unroll
    for (int j = 0; j < 4; ++j) {
        int f4 = (j << 8) + tid, row = f4 >> 4, c4 = f4 & 15;
        float4 q = Qg4[base4 + (size_t)(q0 + row) * rs4 + c4];
        unsigned short h0 = f2bf(q.x), h1 = f2bf(q.y), h2 = f2bf(q.z), h3 = f2bf(q.w);
        short4 hv = make_short4((short)h0, (short)h1, (short)h2, (short)h3);
        short4 lv = make_short4((short)f2bf(q.x - bf2f(h0)), (short)f2bf(q.y - bf2f(h1)),
                                (short)f2bf(q.z - bf2f(h2)), (short)f2bf(q.w - bf2f(h3)));
        *(short4*)&Qh[row * LSTR + c4 * 4] = hv;
        *(short4*)&Ql[row * LSTR + c4 * 4] = lv;
    }
    __syncthreads();

    // persistent Q A-frags: A[m=a][k=quad*8+j], k-chunks of 32
    bf16x8 aQh[2], aQl[2];
    #pragma unroll
    for (int ks = 0; ks < 2; ++ks) {
        aQh[ks] = *(const bf16x8*)&Qh[(m0 + a) * LSTR + ks * 32 + quad * 8];
        aQl[ks] = *(const bf16x8*)&Ql[(m0 + a) * LSTR + ks * 32 + quad * 8];
    }

    f32x4 oacc[4];
    #pragma unroll
    for (int n = 0; n < 4; ++n) oacc[n] = (f32x4){0.f, 0.f, 0.f, 0.f};
    float den[4] = {0.f, 0.f, 0.f, 0.f};

    for (int kt = 0; kt <= qt; ++kt) {
        __syncthreads();   // B1: prev PV done with Sh/Sl/Vt before K/Vf overwrite

        // ---- stage K hi/lo + V f32 ----
        #pragma unroll
        for (int j = 0; j < 4; ++j) {
            int f4 = (j << 8) + tid, row = f4 >> 4, c4 = f4 & 15;
            size_t g = base4 + (size_t)(kt * 64 + row) * rs4 + c4;
            float4 k = Kg4[g];
            unsigned short h0 = f2bf(k.x), h1 = f2bf(k.y), h2 = f2bf(k.z), h3 = f2bf(k.w);
            *(short4*)&Kh[row * LSTR + c4 * 4] =
                make_short4((short)h0, (short)h1, (short)h2, (short)h3);
            *(short4*)&Kl[row * LSTR + c4 * 4] =
                make_short4((short)f2bf(k.x - bf2f(h0)), (short)f2bf(k.y - bf2f(h1)),
                            (short)f2bf(k.z - bf2f(h2)), (short)f2bf(k.w - bf2f(h3)));
            *(float4*)&Vf[row * 68 + c4 * 4] = Vg4[g];
        }
        __syncthreads();   // B2: Vf written

        // ---- transpose V: column read -> bf16 -> V^T rows ----
        {
            int lv = tid & 63, w = tid >> 6, kb = w * 16;
            union { int4 v; unsigned short s[8]; } p0, p1;
            #pragma unroll
            for (int i = 0; i < 8; ++i) p0.s[i] = f2bf(Vf[(kb + i) * 68 + lv]);
            #pragma unroll
            for (int i = 0; i < 8; ++i) p1.s[i] = f2bf(Vf[(kb + 8 + i) * 68 + lv]);
            *(int4*)&Vt[lv * LSTR + kb]     = p0.v;
            *(int4*)&Vt[lv * LSTR + kb + 8] = p1.v;
        }
        __syncthreads();   // B3: Kh/Kl/Vt ready; Vf reads drained

        // ---- QK^T: S = Qh*Kh + Qh*Kl + Ql*Kh ----
        f32x4 sacc[4];
        #pragma unroll
        for (int n = 0; n < 4; ++n) sacc[n] = (f32x4){0.f, 0.f, 0.f, 0.f};
        #pragma unroll
        for (int n = 0; n < 4; ++n) {
            #pragma unroll
            for (int ks = 0; ks < 2; ++ks) {
                bf16x8 bKhf = *(const bf16x8*)&Kh[(n * 16 + a) * LSTR + ks * 32 + quad * 8];
                bf16x8 bKlf = *(const bf16x8*)&Kl[(n * 16 + a) * LSTR + ks * 32 + quad * 8];
                sacc[n] = __builtin_amdgcn_mfma_f32_16x16x32_bf16(aQh[ks], bKhf, sacc[n], 0, 0, 0);
                sacc[n] = __builtin_amdgcn_mfma_f32_16x16x32_bf16(aQh[ks], bKlf, sacc[n], 0, 0, 0);
                sacc[n] = __builtin_amdgcn_mfma_f32_16x16x32_bf16(aQl[ks], bKhf, sacc[n], 0, 0, 0);
            }
        }

        // ---- square, mask, split to bf16 hi/lo, exact-matching denominator ----
        const bool diag = (kt == qt);
        #pragma unroll
        for (int n = 0; n < 4; ++n) {
            #pragma unroll
            for (int r = 0; r < 4; ++r) {
                float dot = sacc[n][r];
                float p = dot * dot;
                int qrow = m0 + quad * 4 + r;       // C/D layout: row=quad*4+reg
                int col  = n * 16 + a;              //            col=lane&15
                if (diag && col > qrow) p = 0.f;
                unsigned short hh = f2bf(p);
                float ph = bf2f(hh);
                unsigned short ll = f2bf(p - ph);
                den[r] += ph + bf2f(ll);            // matches MFMA'd weights exactly
                Sh[qrow * LSTR + col] = (short)hh;
                Sl[qrow * LSTR + col] = (short)ll;
            }
        }
        __syncthreads();   // B4: S tiles ready

        // ---- PV: O += (Sh + Sl) * V ----
        bf16x8 aSh[2], aSl[2];
        #pragma unroll
        for (int ks = 0; ks < 2; ++ks) {
            aSh[ks] = *(const bf16x8*)&Sh[(m0 + a) * LSTR + ks * 32 + quad * 8];
            aSl[ks] = *(const bf16x8*)&Sl[(m0 + a) * LSTR + ks * 32 + quad * 8];
        }
        #pragma unroll
        for (int n = 0; n < 4; ++n) {
            #pragma unroll
            for (int ks = 0; ks < 2; ++ks) {
                bf16x8 bV = *(const bf16x8*)&Vt[(n * 16 + a) * LSTR + ks * 32 + quad * 8];
                oacc[n] = __builtin_amdgcn_mfma_f32_16x16x32_bf16(aSh[ks], bV, oacc[n], 0, 0, 0);
                oacc[n] = __builtin_amdgcn_mfma_f32_16x16x32_bf16(aSl[ks], bV, oacc[n], 0, 0, 0);
            }
        }
    }

    // ---- denominator reduce across the 16 lanes of each quad, divide, store ----
    #pragma unroll
    for (int r = 0; r < 4; ++r) {
        den[r] += __shfl_xor(den[r], 1);
        den[r] += __shfl_xor(den[r], 2);
        den[r] += __shfl_xor(den[r], 4);
        den[r] += __shfl_xor(den[r], 8);
    }
    float invz[4];
    #pragma unroll
    for (int r = 0; r < 4; ++r) invz[r] = 1.0f / (den[r] + 1e-5f);

    #pragma unroll
    for (int n = 0; n < 4; ++n) {
        #pragma unroll
        for (int r = 0; r < 4; ++r) {
            int t = q0 + m0 + quad * 4 + r;
            int v = n * 16 + a;
            Og[(((size_t)b * T + t) * H + h) * DH + v] = oacc[n][r] * invz[r];
        }
    }
}

extern "C" void kernel_launch(void* const* d_in, const int* in_sizes, int n_in,
                              void* d_out, int out_size, void* d_ws, size_t ws_size,
                              hipStream_t stream) {
    const float* Q = (const float*)d_in[0];
    const float* K = (const float*)d_in[1];
    const float* V = (const float*)d_in[2];
    float* O = (float*)d_out;
    const int B = 2, T = 2048, H = 8;
    dim3 grid(512);
    attn_pow2_mfma<<<grid, NT, 0, stream>>>(Q, K, V, O, B, T, H);
}

// Round 4
// 98.577 us; speedup vs baseline: 3.9099x; 1.4666x over previous
//
#include <hip/hip_runtime.h>
#include <hip/hip_fp16.h>

typedef __attribute__((ext_vector_type(8))) _Float16 f16x8;
typedef __attribute__((ext_vector_type(8))) unsigned short u16x8;
typedef __attribute__((ext_vector_type(4))) float f32x4;

constexpr int NT = 256;
constexpr int TILE_SHORTS = 4096;   // 64 rows x 64 fp16 (8KB image, XOR-swizzled)
constexpr int SSTR = 72;            // per-wave S row stride (shorts)

// phys chunk swizzle: row r, logical 16B-chunk c -> short offset
__device__ __forceinline__ int swzoff(int row, int c) {
    return row * 64 + (((c) ^ (row & 7)) << 3);
}

__device__ __forceinline__ unsigned short f2h_u(float x) {
    return __half_as_ushort(__float2half(x));
}

// ============ pre-pass: f32 -> fp16 swizzled tile images in ws ============
__global__ __launch_bounds__(256, 4) void prepass(
    const float* __restrict__ Kg, const float* __restrict__ Vg,
    unsigned short* __restrict__ Kw, unsigned short* __restrict__ Vw)
{
    __shared__ __align__(16) float Vl[64 * 68];
    const int tile = blockIdx.x;      // 0..31
    const int bh   = blockIdx.y;      // 0..15
    const int b = bh >> 3, h = bh & 7;
    const int tid = threadIdx.x;
    // element offset of (t = tile*64, d = 0); time-row stride = H*D = 512 floats
    const size_t gbase = (((size_t)b * 2048 + tile * 64) * 8 + h) * 64;

    // stage V tile f32 into LDS (coalesced)
    #pragma unroll
    for (int j = 0; j < 4; ++j) {
        int id = j * 256 + tid, row = id >> 4, c4 = id & 15;
        *(float4*)&Vl[row * 68 + c4 * 4] =
            *(const float4*)&Vg[gbase + (size_t)row * 512 + c4 * 4];
    }

    // K: convert rows directly (each thread: 2 chunks of 8 floats)
    unsigned short* Ko = Kw + (size_t)(bh * 32 + tile) * TILE_SHORTS;
    #pragma unroll
    for (int j = 0; j < 2; ++j) {
        int id = j * 256 + tid, row = id >> 3, c = id & 7;
        const float* src = &Kg[gbase + (size_t)row * 512 + c * 8];
        float4 x = *(const float4*)src, y = *(const float4*)(src + 4);
        u16x8 o;
        o[0] = f2h_u(x.x); o[1] = f2h_u(x.y); o[2] = f2h_u(x.z); o[3] = f2h_u(x.w);
        o[4] = f2h_u(y.x); o[5] = f2h_u(y.y); o[6] = f2h_u(y.z); o[7] = f2h_u(y.w);
        *(u16x8*)&Ko[swzoff(row, c)] = o;
    }
    __syncthreads();

    // V^T: read columns from LDS (conflict-free: lanes span consecutive floats),
    // convert, write swizzled
    unsigned short* Vo = Vw + (size_t)(bh * 32 + tile) * TILE_SHORTS;
    #pragma unroll
    for (int j = 0; j < 2; ++j) {
        int id = j * 256 + tid, vrow = id >> 3, c = id & 7;
        u16x8 o;
        #pragma unroll
        for (int i = 0; i < 8; ++i) o[i] = f2h_u(Vl[(c * 8 + i) * 68 + vrow]);
        *(u16x8*)&Vo[swzoff(vrow, c)] = o;
    }
}

// ============ main kernel ============
__global__ __launch_bounds__(NT, 3) void attn_pow2_f16(
    const float* __restrict__ Qg,
    const unsigned short* __restrict__ Kw, const unsigned short* __restrict__ Vw,
    float* __restrict__ Og)
{
    __shared__ __align__(16) unsigned short lds[4 * TILE_SHORTS + 4 * 16 * SSTR]; // 41984 B
    unsigned short* const Kb = lds;                       // 2 buffers
    unsigned short* const Vb = lds + 2 * TILE_SHORTS;     // 2 buffers
    const int tid  = threadIdx.x;
    const int lane = tid & 63;
    const int wave = tid >> 6;
    const int a    = lane & 15;
    const int quad = lane >> 4;
    const int m0   = wave * 16;
    unsigned short* const Sme = lds + 4 * TILE_SHORTS + wave * (16 * SSTR);

    // heavy+light pairing swizzle (bijection over 512 blocks)
    int r0 = (int)blockIdx.x;
    int wr = (r0 < 256) ? r0 : (767 - r0);
    const int qt = 31 - (wr >> 4);
    const int bh = wr & 15;
    const int b = bh >> 3, h = bh & 7;
    const int q0 = qt * 64;

    // ---- Q A-frags straight from global f32 (one-time, per-lane rows) ----
    f16x8 aQ[2];
    {
        const size_t qrowbase = (((size_t)b * 2048 + q0 + m0 + a) * 8 + h) * 64;
        #pragma unroll
        for (int ks = 0; ks < 2; ++ks) {
            const float* src = &Qg[qrowbase + ks * 32 + quad * 8];
            float4 x = *(const float4*)src, y = *(const float4*)(src + 4);
            u16x8 o;
            o[0] = f2h_u(x.x); o[1] = f2h_u(x.y); o[2] = f2h_u(x.z); o[3] = f2h_u(x.w);
            o[4] = f2h_u(y.x); o[5] = f2h_u(y.y); o[6] = f2h_u(y.z); o[7] = f2h_u(y.w);
            aQ[ks] = __builtin_bit_cast(f16x8, o);
        }
    }

    const unsigned short* Ktiles = Kw + (size_t)bh * 32 * TILE_SHORTS;
    const unsigned short* Vtiles = Vw + (size_t)bh * 32 * TILE_SHORTS;

    // register-staged tile prefetch: each thread owns 32B of the K image and
    // 32B of the V image (byte-identical copy; swizzle already baked in ws)
    u16x8 rK[2], rV[2];
    auto gload = [&](int kt) {
        const u16x8* kg = (const u16x8*)(Ktiles + (size_t)kt * TILE_SHORTS);
        const u16x8* vg = (const u16x8*)(Vtiles + (size_t)kt * TILE_SHORTS);
        rK[0] = kg[tid * 2]; rK[1] = kg[tid * 2 + 1];
        rV[0] = vg[tid * 2]; rV[1] = vg[tid * 2 + 1];
    };
    gload(0);

    f32x4 oacc[4];
    #pragma unroll
    for (int n = 0; n < 4; ++n) oacc[n] = (f32x4){0.f, 0.f, 0.f, 0.f};
    float den[4] = {0.f, 0.f, 0.f, 0.f};

    for (int kt = 0; kt <= qt; ++kt) {
        const int buf = kt & 1;
        __syncthreads();   // B0: all waves finished reading buf (WAR protection)

        u16x8* kd = (u16x8*)(Kb + buf * TILE_SHORTS);
        u16x8* vd = (u16x8*)(Vb + buf * TILE_SHORTS);
        kd[tid * 2] = rK[0]; kd[tid * 2 + 1] = rK[1];   // contiguous b128: conflict-free
        vd[tid * 2] = rV[0]; vd[tid * 2 + 1] = rV[1];
        if (kt < qt) gload(kt + 1);                      // latency hides under compute

        __syncthreads();   // B1: buf image complete, visible to all waves

        const unsigned short* Kc = Kb + buf * TILE_SHORTS;
        const unsigned short* Vc = Vb + buf * TILE_SHORTS;

        // ---- QK^T (fp16 MFMA) ----
        f32x4 sacc[4];
        #pragma unroll
        for (int n = 0; n < 4; ++n) sacc[n] = (f32x4){0.f, 0.f, 0.f, 0.f};
        #pragma unroll
        for (int n = 0; n < 4; ++n) {
            #pragma unroll
            for (int ks = 0; ks < 2; ++ks) {
                f16x8 bK = *(const f16x8*)&Kc[swzoff(n * 16 + a, ks * 4 + quad)];
                sacc[n] = __builtin_amdgcn_mfma_f32_16x16x32_f16(aQ[ks], bK, sacc[n], 0, 0, 0);
            }
        }

        // ---- square, mask (diag only), accumulate den, store S (own strip) ----
        const bool diag = (kt == qt);
        #pragma unroll
        for (int n = 0; n < 4; ++n) {
            const int col = n * 16 + a;
            #pragma unroll
            for (int r = 0; r < 4; ++r) {
                float d0 = sacc[n][r];
                float p = d0 * d0;
                if (diag && col > (m0 + quad * 4 + r)) p = 0.f;
                den[r] += p;
                Sme[(quad * 4 + r) * SSTR + col] = f2h_u(p);
            }
        }

        // ---- PV: O += S * V^T  (S exchange is intra-wave; no barrier) ----
        f16x8 aS[2];
        #pragma unroll
        for (int ks = 0; ks < 2; ++ks)
            aS[ks] = *(const f16x8*)&Sme[a * SSTR + ks * 32 + quad * 8];
        #pragma unroll
        for (int n = 0; n < 4; ++n) {
            #pragma unroll
            for (int ks = 0; ks < 2; ++ks) {
                f16x8 bV = *(const f16x8*)&Vc[swzoff(n * 16 + a, ks * 4 + quad)];
                oacc[n] = __builtin_amdgcn_mfma_f32_16x16x32_f16(aS[ks], bV, oacc[n], 0, 0, 0);
            }
        }
    }

    // ---- reduce den over the 16 a-lanes of each quad, divide, store ----
    #pragma unroll
    for (int r = 0; r < 4; ++r) {
        den[r] += __shfl_xor(den[r], 1);
        den[r] += __shfl_xor(den[r], 2);
        den[r] += __shfl_xor(den[r], 4);
        den[r] += __shfl_xor(den[r], 8);
    }
    float invz[4];
    #pragma unroll
    for (int r = 0; r < 4; ++r) invz[r] = 1.0f / (den[r] + 1e-5f);

    #pragma unroll
    for (int n = 0; n < 4; ++n) {
        #pragma unroll
        for (int r = 0; r < 4; ++r) {
            int t = q0 + m0 + quad * 4 + r;
            int v = n * 16 + a;
            Og[(((size_t)b * 2048 + t) * 8 + h) * 64 + v] = oacc[n][r] * invz[r];
        }
    }
}

extern "C" void kernel_launch(void* const* d_in, const int* in_sizes, int n_in,
                              void* d_out, int out_size, void* d_ws, size_t ws_size,
                              hipStream_t stream) {
    const float* Q = (const float*)d_in[0];
    const float* K = (const float*)d_in[1];
    const float* V = (const float*)d_in[2];
    float* O = (float*)d_out;
    unsigned short* Kw = (unsigned short*)d_ws;                 // 4 MB
    unsigned short* Vw = Kw + (size_t)16 * 32 * TILE_SHORTS;    // 4 MB

    prepass<<<dim3(32, 16), 256, 0, stream>>>(K, V, Kw, Vw);
    attn_pow2_f16<<<dim3(512), NT, 0, stream>>>(Q, Kw, Vw, O);
}

// Round 5
// 96.824 us; speedup vs baseline: 3.9807x; 1.0181x over previous
//
#include <hip/hip_runtime.h>
#include <hip/hip_fp16.h>

typedef __attribute__((ext_vector_type(8))) _Float16 f16x8;
typedef __attribute__((ext_vector_type(4))) _Float16 f16x4;
typedef __attribute__((ext_vector_type(8))) unsigned short u16x8;
typedef __attribute__((ext_vector_type(4))) float f32x4;

constexpr int NT = 256;
constexpr int TILE_SHORTS = 4096;   // 64 rows x 64 fp16 = 8KB tile image

// phys 16B-chunk swizzle: row r, logical chunk c (0..7) -> short offset
__device__ __forceinline__ int swzoff(int row, int c) {
    return row * 64 + ((c ^ (row & 7)) << 3);
}
__device__ __forceinline__ unsigned short f2h_u(float x) {
    return __half_as_ushort(__float2half(x));
}

// ============ pre-pass: f32 -> fp16 swizzled tile images in ws ============
__global__ __launch_bounds__(256, 4) void prepass(
    const float* __restrict__ Kg, const float* __restrict__ Vg,
    unsigned short* __restrict__ Kw, unsigned short* __restrict__ Vw)
{
    __shared__ __align__(16) float Vl[64 * 68];
    const int tile = blockIdx.x;      // 0..31
    const int bh   = blockIdx.y;      // 0..15
    const int b = bh >> 3, h = bh & 7;
    const int tid = threadIdx.x;
    const size_t gbase = (((size_t)b * 2048 + tile * 64) * 8 + h) * 64;

    // stage V tile f32 into LDS (coalesced)
    #pragma unroll
    for (int j = 0; j < 4; ++j) {
        int id = j * 256 + tid, row = id >> 4, c4 = id & 15;
        *(float4*)&Vl[row * 68 + c4 * 4] =
            *(const float4*)&Vg[gbase + (size_t)row * 512 + c4 * 4];
    }

    // K image: row-major fp16, 16B chunks XOR-swizzled (A-frag b128 reads)
    unsigned short* Ko = Kw + (size_t)(bh * 32 + tile) * TILE_SHORTS;
    #pragma unroll
    for (int j = 0; j < 2; ++j) {
        int id = j * 256 + tid, row = id >> 3, c = id & 7;
        const float* src = &Kg[gbase + (size_t)row * 512 + c * 8];
        float4 x = *(const float4*)src, y = *(const float4*)(src + 4);
        u16x8 o;
        o[0] = f2h_u(x.x); o[1] = f2h_u(x.y); o[2] = f2h_u(x.z); o[3] = f2h_u(x.w);
        o[4] = f2h_u(y.x); o[5] = f2h_u(y.y); o[6] = f2h_u(y.z); o[7] = f2h_u(y.w);
        *(u16x8*)&Ko[swzoff(row, c)] = o;
    }
    __syncthreads();

    // V^T image with permuted k-order: k' = (k&12)>>2 stays inner... mapping:
    // store at k' = quad*16 + c*4 + i  the element k = c*16 + quad*4 + i,
    // so one b128 at chunk (quad*2 [+1]) yields the 4 B-frags of 16x16x16 PV.
    unsigned short* Vo = Vw + (size_t)(bh * 32 + tile) * TILE_SHORTS;
    #pragma unroll
    for (int j = 0; j < 2; ++j) {
        int id = j * 256 + tid, vrow = id >> 3, g = id & 7;
        u16x8 o;
        #pragma unroll
        for (int jj = 0; jj < 8; ++jj) {
            int kk = ((g & 1) * 2 + (jj >> 2)) * 16 + (g >> 1) * 4 + (jj & 3);
            o[jj] = f2h_u(Vl[kk * 68 + vrow]);
        }
        *(u16x8*)&Vo[swzoff(vrow, g)] = o;
    }
}

// ============ main kernel ============
__global__ __launch_bounds__(NT, 3) void attn_pow2_f16(
    const float* __restrict__ Qg,
    const unsigned short* __restrict__ Kw, const unsigned short* __restrict__ Vw,
    float* __restrict__ Og)
{
    __shared__ __align__(16) unsigned short lds[4 * TILE_SHORTS];  // 32 KiB
    unsigned short* const Kb = lds;                    // 2 buffers
    unsigned short* const Vb = lds + 2 * TILE_SHORTS;  // 2 buffers
    const int tid  = threadIdx.x;
    const int lane = tid & 63;
    const int wave = tid >> 6;
    const int a    = lane & 15;
    const int quad = lane >> 4;
    const int m0   = wave * 16;

    // heavy+light pairing swizzle (bijection over 512 blocks)
    int r0 = (int)blockIdx.x;
    int wr = (r0 < 256) ? r0 : (767 - r0);
    const int qt = 31 - (wr >> 4);
    const int bh = wr & 15;
    const int b = bh >> 3, h = bh & 7;
    const int q0 = qt * 64;

    // ---- Q B-frags from global f32: B[n=q=a][k=d=ks*32+quad*8+j] ----
    f16x8 bQ[2];
    {
        const size_t qrowbase = (((size_t)b * 2048 + q0 + m0 + a) * 8 + h) * 64;
        #pragma unroll
        for (int ks = 0; ks < 2; ++ks) {
            const float* src = &Qg[qrowbase + ks * 32 + quad * 8];
            float4 x = *(const float4*)src, y = *(const float4*)(src + 4);
            u16x8 o;
            o[0] = f2h_u(x.x); o[1] = f2h_u(x.y); o[2] = f2h_u(x.z); o[3] = f2h_u(x.w);
            o[4] = f2h_u(y.x); o[5] = f2h_u(y.y); o[6] = f2h_u(y.z); o[7] = f2h_u(y.w);
            bQ[ks] = __builtin_bit_cast(f16x8, o);
        }
    }

    const unsigned short* Ktiles = Kw + (size_t)bh * 32 * TILE_SHORTS;
    const unsigned short* Vtiles = Vw + (size_t)bh * 32 * TILE_SHORTS;

    // register-staged tile prefetch (byte-copy of pre-swizzled images)
    u16x8 rK[2], rV[2];
    auto gload = [&](int kt) {
        const u16x8* kg = (const u16x8*)(Ktiles + (size_t)kt * TILE_SHORTS);
        const u16x8* vg = (const u16x8*)(Vtiles + (size_t)kt * TILE_SHORTS);
        rK[0] = kg[tid * 2]; rK[1] = kg[tid * 2 + 1];
        rV[0] = vg[tid * 2]; rV[1] = vg[tid * 2 + 1];
    };
    gload(0);

    f32x4 oacc[4];
    #pragma unroll
    for (int n = 0; n < 4; ++n) oacc[n] = (f32x4){0.f, 0.f, 0.f, 0.f};
    float den_l = 0.f;

    union U8 { u16x8 u; f16x4 q[2]; };

    for (int kt = 0; kt <= qt; ++kt) {
        const int buf = kt & 1;
        u16x8* kd = (u16x8*)(Kb + buf * TILE_SHORTS);
        u16x8* vd = (u16x8*)(Vb + buf * TILE_SHORTS);
        kd[tid * 2] = rK[0]; kd[tid * 2 + 1] = rK[1];
        vd[tid * 2] = rV[0]; vd[tid * 2 + 1] = rV[1];
        __syncthreads();   // single barrier: buf complete; WAR is 2 barriers back
        if (kt < qt) gload(kt + 1);   // drains during this tile's compute

        const unsigned short* Kc = Kb + buf * TILE_SHORTS;
        const unsigned short* Vc = Vb + buf * TILE_SHORTS;

        // ---- S^T = K·Q^T per 16-row k-strip: C-layout == A-layout of S ----
        f32x4 sacc[4];
        #pragma unroll
        for (int s = 0; s < 4; ++s) sacc[s] = (f32x4){0.f, 0.f, 0.f, 0.f};
        #pragma unroll
        for (int s = 0; s < 4; ++s) {
            #pragma unroll
            for (int ks = 0; ks < 2; ++ks) {
                f16x8 aK = *(const f16x8*)&Kc[swzoff(s * 16 + a, ks * 4 + quad)];
                sacc[s] = __builtin_amdgcn_mfma_f32_16x16x32_f16(aK, bQ[ks], sacc[s], 0, 0, 0);
            }
        }

        // ---- square, mask (diag), den, convert in-register ----
        const bool diag = (kt == qt);
        f16x4 aS[4];
        #pragma unroll
        for (int s = 0; s < 4; ++s) {
            float p[4];
            #pragma unroll
            for (int r = 0; r < 4; ++r) {
                float d0 = sacc[s][r];
                float v = d0 * d0;
                if (diag && (s * 16 + quad * 4 + r) > (m0 + a)) v = 0.f;
                p[r] = v;
            }
            den_l += (p[0] + p[1]) + (p[2] + p[3]);
            aS[s] = (f16x4){(_Float16)p[0], (_Float16)p[1], (_Float16)p[2], (_Float16)p[3]};
        }

        // ---- PV: O += S·V via 16x16x16, S^T C-regs feed A directly ----
        #pragma unroll
        for (int n = 0; n < 4; ++n) {
            const int vrow = n * 16 + a;
            U8 va, vb;
            va.u = *(const u16x8*)&Vc[swzoff(vrow, quad * 2)];
            vb.u = *(const u16x8*)&Vc[swzoff(vrow, quad * 2 + 1)];
            oacc[n] = __builtin_amdgcn_mfma_f32_16x16x16f16(aS[0], va.q[0], oacc[n], 0, 0, 0);
            oacc[n] = __builtin_amdgcn_mfma_f32_16x16x16f16(aS[1], va.q[1], oacc[n], 0, 0, 0);
            oacc[n] = __builtin_amdgcn_mfma_f32_16x16x16f16(aS[2], vb.q[0], oacc[n], 0, 0, 0);
            oacc[n] = __builtin_amdgcn_mfma_f32_16x16x16f16(aS[3], vb.q[1], oacc[n], 0, 0, 0);
        }
    }

    // ---- den: reduce across quads (same q=a), then gather per output row ----
    den_l += __shfl_xor(den_l, 16);
    den_l += __shfl_xor(den_l, 32);

    float invz[4];
    #pragma unroll
    for (int r = 0; r < 4; ++r) {
        float dq = __shfl(den_l, quad * 4 + r);   // lane holding a == quad*4+r
        invz[r] = 1.0f / (dq + 1e-5f);
    }

    #pragma unroll
    for (int n = 0; n < 4; ++n) {
        #pragma unroll
        for (int r = 0; r < 4; ++r) {
            int t = q0 + m0 + quad * 4 + r;
            int v = n * 16 + a;
            Og[(((size_t)b * 2048 + t) * 8 + h) * 64 + v] = oacc[n][r] * invz[r];
        }
    }
}

extern "C" void kernel_launch(void* const* d_in, const int* in_sizes, int n_in,
                              void* d_out, int out_size, void* d_ws, size_t ws_size,
                              hipStream_t stream) {
    const float* Q = (const float*)d_in[0];
    const float* K = (const float*)d_in[1];
    const float* V = (const float*)d_in[2];
    float* O = (float*)d_out;
    unsigned short* Kw = (unsigned short*)d_ws;                 // 4 MB
    unsigned short* Vw = Kw + (size_t)16 * 32 * TILE_SHORTS;    // 4 MB

    prepass<<<dim3(32, 16), 256, 0, stream>>>(K, V, Kw, Vw);
    attn_pow2_f16<<<dim3(512), NT, 0, stream>>>(Q, Kw, Vw, O);
}